// Round 5
// baseline (612.281 us; speedup 1.0000x reference)
//
#include <hip/hip_runtime.h>
#include <hip/hip_bf16.h>

// ---------------------------------------------------------------------------
// HRAInjectedLinear: out = x @ (W * prod_i (I - 2 u_i u_i^T))^T
//   prep:    d_ij = hu_i . hu_j  ->  inv_i = rsqrt(d_ii), G_ij = d_ij inv_i inv_j
//   Y = W U            (wu_gemv, scales folded post-loop)
//   Wn = bf16(W - 2 V U^T)  (wn_cast: per-row recurrence v fused in)
//   Xb = bf16(x)            (cast_x)
//   out = Xb @ Wn^T    (gemm256: 256x256 tile, 8 waves, r2's 2-barrier
//                       counted-vmcnt schedule, 32x32x16 MFMA, st_16x32
//                       LDS swizzle, XCD swizzle, setprio)
//   RACE FIX vs r4: regions split by A-rows (i), not k-steps — ALL B-frag
//   reads happen before the mid-barrier, so restaging bb.B after it is legal
//   (this is exactly r2's proven hazard structure).
// ---------------------------------------------------------------------------

#define D_IN   4096
#define D_OUT  4096
#define R_HH   8
#define M_ROWS 8192   // B*S = 4*2048

typedef short bf16x8  __attribute__((ext_vector_type(8)));
typedef float f32x4   __attribute__((ext_vector_type(4)));
typedef float f32x16  __attribute__((ext_vector_type(16)));

__device__ inline unsigned short f2bf(float f) {
    unsigned int x = __float_as_uint(f);
    unsigned int lsb = (x >> 16) & 1u;
    x += 0x7fffu + lsb;                 // round-to-nearest-even
    return (unsigned short)(x >> 16);
}

__device__ inline void async16(const unsigned short* g, char* l) {
    __builtin_amdgcn_global_load_lds(
        (const __attribute__((address_space(1))) void*)g,
        (__attribute__((address_space(3))) void*)l,
        16, 0, 0);
}

// --- kernel 1: prep — raw Gram dots of hra_u columns -> G (normalized) + inv
__global__ __launch_bounds__(1024) void prep(const float* __restrict__ hu,
                                             float* __restrict__ G,
                                             float* __restrict__ inv8) {
    float d[36];
    #pragma unroll
    for (int p = 0; p < 36; p++) d[p] = 0.f;
    for (int r = threadIdx.x; r < D_IN; r += 1024) {
        const float4* h4 = (const float4*)&hu[r * R_HH];
        float4 a = h4[0], b = h4[1];
        float h[8] = {a.x, a.y, a.z, a.w, b.x, b.y, b.z, b.w};
        int p = 0;
        #pragma unroll
        for (int i = 0; i < 8; i++)
            #pragma unroll
            for (int j = i; j < 8; j++)
                d[p++] += h[i] * h[j];
    }
    #pragma unroll
    for (int p = 0; p < 36; p++)
        #pragma unroll
        for (int off = 32; off > 0; off >>= 1)
            d[p] += __shfl_down(d[p], off, 64);
    __shared__ float red[16 * 36];
    const int wave = threadIdx.x >> 6, lane = threadIdx.x & 63;
    if (lane == 0)
        #pragma unroll
        for (int p = 0; p < 36; p++) red[wave * 36 + p] = d[p];
    __syncthreads();
    __shared__ float dd[36];
    if (threadIdx.x < 36) {
        float s = 0.f;
        #pragma unroll
        for (int w = 0; w < 16; w++) s += red[w * 36 + threadIdx.x];
        dd[threadIdx.x] = s;
    }
    __syncthreads();
    auto idx = [](int a, int b) { return a * 8 + b - (a * (a + 1)) / 2; };
    if (threadIdx.x < 64) {
        const int i = threadIdx.x >> 3, j = threadIdx.x & 7;
        const int a = i < j ? i : j, b = i < j ? j : i;
        const float gi = rsqrtf(dd[idx(i, i)]);
        const float gj = rsqrtf(dd[idx(j, j)]);
        G[threadIdx.x] = dd[idx(a, b)] * gi * gj;
        if (j == 0) inv8[i] = gi;
    }
}

// --- kernel 2: Y = W U  (one block per row of W; scales folded post-loop) --
__global__ void wu_gemv(const float* __restrict__ W, const float* __restrict__ hu,
                        const float* __restrict__ inv8, float* __restrict__ Y) {
    const int o = blockIdx.x;
    const float* wrow = W + (size_t)o * D_IN;
    float acc[8] = {0,0,0,0,0,0,0,0};
    for (int k = threadIdx.x; k < D_IN; k += 256) {
        float w = wrow[k];
        const float4* u4 = (const float4*)&hu[k * R_HH];
        float4 a = u4[0], b = u4[1];
        acc[0] += w * a.x; acc[1] += w * a.y; acc[2] += w * a.z; acc[3] += w * a.w;
        acc[4] += w * b.x; acc[5] += w * b.y; acc[6] += w * b.z; acc[7] += w * b.w;
    }
    __shared__ float red[8 * 256];
    #pragma unroll
    for (int j = 0; j < 8; j++) red[j * 256 + threadIdx.x] = acc[j];
    __syncthreads();
    for (int off = 128; off > 0; off >>= 1) {
        if (threadIdx.x < off)
            #pragma unroll
            for (int j = 0; j < 8; j++)
                red[j * 256 + threadIdx.x] += red[j * 256 + threadIdx.x + off];
        __syncthreads();
    }
    if (threadIdx.x < 8)
        Y[(size_t)o * R_HH + threadIdx.x] = red[threadIdx.x * 256] * inv8[threadIdx.x];
}

// --- kernel 3: Wn = bf16(W - 2 V U^T); recurrence + u-scale fused ----------
__global__ void wn_cast(const float* __restrict__ W, const float* __restrict__ hu,
                        const float* __restrict__ inv8, const float* __restrict__ Y,
                        const float* __restrict__ G, unsigned short* __restrict__ Wn) {
    const int o = blockIdx.x;
    __shared__ float gs[64];
    __shared__ float ys[8];
    __shared__ float is[8];
    if (threadIdx.x < 64) gs[threadIdx.x] = G[threadIdx.x];
    else if (threadIdx.x < 72) ys[threadIdx.x - 64] = Y[(size_t)o * R_HH + threadIdx.x - 64];
    else if (threadIdx.x < 80) is[threadIdx.x - 72] = inv8[threadIdx.x - 72];
    __syncthreads();
    // per-row recurrence (redundant per thread, ~100 FLOP):
    // vrec_i = y_i - 2 sum_{j<i} G[j][i] vrec_j ; then scale by inv_i
    float v[8];
    #pragma unroll
    for (int i = 0; i < 8; i++) {
        float t = ys[i];
        #pragma unroll
        for (int j = 0; j < 8; j++)
            if (j < i) t -= 2.0f * gs[j * 8 + i] * v[j];
        v[i] = t;
    }
    #pragma unroll
    for (int i = 0; i < 8; i++) v[i] *= is[i];
    const float4* wrow = (const float4*)(W + (size_t)o * D_IN);
    ushort4* wnrow = (ushort4*)(Wn + (size_t)o * D_IN);
    for (int k4 = threadIdx.x; k4 < D_IN / 4; k4 += 256) {
        float4 wv = wrow[k4];
        float wa[4] = {wv.x, wv.y, wv.z, wv.w};
        float out[4];
        #pragma unroll
        for (int e = 0; e < 4; e++) {
            const int k = k4 * 4 + e;
            const float4* u4 = (const float4*)&hu[k * R_HH];
            float4 ua = u4[0], ub = u4[1];
            float corr = v[0]*ua.x + v[1]*ua.y + v[2]*ua.z + v[3]*ua.w
                       + v[4]*ub.x + v[5]*ub.y + v[6]*ub.z + v[7]*ub.w;
            out[e] = wa[e] - 2.0f * corr;
        }
        ushort4 r;
        r.x = f2bf(out[0]); r.y = f2bf(out[1]); r.z = f2bf(out[2]); r.w = f2bf(out[3]);
        wnrow[k4] = r;
    }
}

// --- kernel 4: Xb = bf16(x), grid-stride ------------------------------------
__global__ void cast_x(const float4* __restrict__ x, ushort4* __restrict__ xb, int n4) {
    for (int g = blockIdx.x * 256 + threadIdx.x; g < n4; g += gridDim.x * 256) {
        float4 f = x[g];
        ushort4 r;
        r.x = f2bf(f.x); r.y = f2bf(f.y); r.z = f2bf(f.z); r.w = f2bf(f.w);
        xb[g] = r;
    }
}

// --- kernel 5: C = A B^T, 256x256 tile, 8 waves, 2-barrier counted-vmcnt ---
//
// r2's proven 2-barrier schedule with 32x32x16 MFMA (pipe 2495 vs 2176 TF).
//
// LDS (dynamic, 128 KiB), st_16x32 swizzle via pre-swizzled global source +
// swizzled ds_read addr (both-sides, m173/m201 pattern):
//   A: [buf][ks][row 0..255][col 0..31] bf16, bytes [0, 65536)
//   B: same, bytes [65536, 131072)
//   LDS in-row byte b of row r holds global k-byte b ^ ((r&8)?32:0).
//
// Per-wave: output 128x64 = 4x2 tiles of 32x32; 32 MFMA 32x32x16 per K-tile
// over ksteps s=0..3 (global k = s*16..+15).
// Fragments: row/col = base + (lane&31), k-byte = ((s&1)*32+(lane>>5)*16)
//   ^ ((lane&8)?32:0), section (s>>1).  [contiguous-8 per lane; gfx942
//   32x32x16-fp8 precedent + m97 16x16x32 analogy]
// C/D 32x32 [m74/m101]: col=lane&31, row=(reg&3)+8*(reg>>2)+4*(lane>>5).
//
// Schedule per K-tile kt (buf bb = kt&1) — 2 barriers, split by A-rows:
//   region 1: ds a[i=0,1][s0..3] (8) + ALL b[j][s0..3] (8); stageA(kt+1,0);
//     8 MFMA (i01,s01); stageA(kt+1,1); 8 MFMA (i01,s23); mid-barrier
//     (ALL bb.B reads done -> bb.B free for restaging)
//   region 2: ds a[i=2,3][s0..3] (8); stageB(kt+2,0); 8 MFMA (i23,s01);
//     stageB(kt+2,1); 8 MFMA (i23,s23); vmcnt(4) [drains A(kt+1,*), keeps
//     B(kt+2,*) in flight; vmcnt(0) last 2 tiles]; boundary barrier.
// ---------------------------------------------------------------------------
__global__ __launch_bounds__(512, 2) void gemm256(
    const unsigned short* __restrict__ A,   // [M][K] bf16 bits
    const unsigned short* __restrict__ B,   // [N][K] bf16 bits
    float* __restrict__ C) {                // [M][N]
    constexpr int K  = D_IN;
    constexpr int NN = D_OUT;
    constexpr int NT = K / 64;              // 64 K-tiles

    extern __shared__ __align__(16) char lds[];

    const int tid  = threadIdx.x;
    const int lane = tid & 63;
    const int wave = tid >> 6;

    // bijective XCD swizzle (512 blocks, 512 % 8 == 0); tm-major chunks
    const int bid = blockIdx.x;
    const int cpx = gridDim.x >> 3;
    const int swz = (bid & 7) * cpx + (bid >> 3);
    const int TN  = NN / 256;               // 16
    const int tm  = swz / TN, tn = swz - tm * TN;

    const size_t rA0 = (size_t)tm * 256;
    const size_t rB0 = (size_t)tn * 256;

    const int wr = (wave >> 2) * 128;       // 2 waves in M
    const int wc = (wave & 3) * 64;         // 4 waves in N

    // staging: per-thread source (pre-swizzled column), linear LDS dest
    const int sRow = tid >> 2;                                  // 0..127
    const int sCol = ((tid & 3) * 8) ^ ((sRow & 8) ? 16 : 0);   // ^16 cols
    const unsigned short* gA = A + (rA0 + sRow) * (size_t)K + sCol;
    const unsigned short* gB = B + (rB0 + sRow) * (size_t)K + sCol;

    auto stageA = [&](int kt, int h) {
        const unsigned short* g = gA + (size_t)(h * 128) * K + kt * 64;
        char* l = lds + (kt & 1) * 32768 + h * 8192 + tid * 16;
        async16(g, l);              // ks = 0 (cols 0..31)
        async16(g + 32, l + 16384); // ks = 1 (cols 32..63)
    };
    auto stageB = [&](int kt, int h) {
        const unsigned short* g = gB + (size_t)(h * 128) * K + kt * 64;
        char* l = lds + 65536 + (kt & 1) * 32768 + h * 8192 + tid * 16;
        async16(g, l);
        async16(g + 32, l + 16384);
    };

    // reader constants (32x32x16 fragments)
    const int xorv = (lane & 8) ? 32 : 0;
    const int k16  = (lane >> 5) * 16;
    const int rbA  = (wr + (lane & 31)) * 64;   // byte row base in A section
    const int rbB  = (wc + (lane & 31)) * 64;   // byte row base in B section

    // frag read: section (s>>1), row base + 32*frag, k-byte ((s&1)*32+k16)^xorv
    auto LDA = [&](int bb, int i, int s) -> bf16x8 {
        return *(const bf16x8*)(lds + bb * 32768 + (s >> 1) * 16384
                                + i * 2048 + rbA + (((s & 1) * 32 + k16) ^ xorv));
    };
    auto LDB = [&](int bb, int j, int s) -> bf16x8 {
        return *(const bf16x8*)(lds + 65536 + bb * 32768 + (s >> 1) * 16384
                                + j * 2048 + rbB + (((s & 1) * 32 + k16) ^ xorv));
    };

    f32x16 acc[4][2];
    #pragma unroll
    for (int i = 0; i < 4; i++)
        #pragma unroll
        for (int j = 0; j < 2; j++)
            acc[i][j] = (f32x16){0.f,0.f,0.f,0.f,0.f,0.f,0.f,0.f,
                                 0.f,0.f,0.f,0.f,0.f,0.f,0.f,0.f};

    // ---- prologue: tile0 fully + tile1 B halves; keep 2 halves in flight ---
    stageA(0, 0); stageA(0, 1); stageB(0, 0); stageB(0, 1);
    stageB(1, 0); stageB(1, 1);
    asm volatile("s_waitcnt vmcnt(4)" ::: "memory");   // tile 0 landed
    __builtin_amdgcn_s_barrier();

    #pragma unroll 2
    for (int kt = 0; kt < NT; ++kt) {
        const int bb = kt & 1;

        bf16x8 a[2][4], b[2][4];
        // ---- region 1: reads a(i=0,1) + ALL b; A-stages; 16 MFMA (i=0,1) --
        #pragma unroll
        for (int i = 0; i < 2; i++)
            #pragma unroll
            for (int s = 0; s < 4; s++) a[i][s] = LDA(bb, i, s);
        #pragma unroll
        for (int j = 0; j < 2; j++)
            #pragma unroll
            for (int s = 0; s < 4; s++) b[j][s] = LDB(bb, j, s);
        if (kt + 1 < NT) stageA(kt + 1, 0);
        __builtin_amdgcn_s_setprio(1);
        #pragma unroll
        for (int s = 0; s < 2; s++)
            #pragma unroll
            for (int i = 0; i < 2; i++)
                #pragma unroll
                for (int j = 0; j < 2; j++)
                    acc[i][j] = __builtin_amdgcn_mfma_f32_32x32x16_bf16(a[i][s], b[j][s], acc[i][j], 0, 0, 0);
        __builtin_amdgcn_s_setprio(0);
        if (kt + 1 < NT) stageA(kt + 1, 1);
        __builtin_amdgcn_s_setprio(1);
        #pragma unroll
        for (int s = 2; s < 4; s++)
            #pragma unroll
            for (int i = 0; i < 2; i++)
                #pragma unroll
                for (int j = 0; j < 2; j++)
                    acc[i][j] = __builtin_amdgcn_mfma_f32_32x32x16_bf16(a[i][s], b[j][s], acc[i][j], 0, 0, 0);
        __builtin_amdgcn_s_setprio(0);

        // ---- mid barrier: all bb.B reads done -> release bb.B -------------
        asm volatile("" ::: "memory");
        __builtin_amdgcn_s_barrier();
        asm volatile("" ::: "memory");

        // ---- region 2: reads a(i=2,3); B-stages; 16 MFMA (i=2,3) ----------
        #pragma unroll
        for (int i = 0; i < 2; i++)
            #pragma unroll
            for (int s = 0; s < 4; s++) a[i][s] = LDA(bb, 2 + i, s);
        if (kt + 2 < NT) stageB(kt + 2, 0);
        __builtin_amdgcn_s_setprio(1);
        #pragma unroll
        for (int s = 0; s < 2; s++)
            #pragma unroll
            for (int i = 0; i < 2; i++)
                #pragma unroll
                for (int j = 0; j < 2; j++)
                    acc[2 + i][j] = __builtin_amdgcn_mfma_f32_32x32x16_bf16(a[i][s], b[j][s], acc[2 + i][j], 0, 0, 0);
        __builtin_amdgcn_s_setprio(0);
        if (kt + 2 < NT) stageB(kt + 2, 1);
        __builtin_amdgcn_s_setprio(1);
        #pragma unroll
        for (int s = 2; s < 4; s++)
            #pragma unroll
            for (int i = 0; i < 2; i++)
                #pragma unroll
                for (int j = 0; j < 2; j++)
                    acc[2 + i][j] = __builtin_amdgcn_mfma_f32_32x32x16_bf16(a[i][s], b[j][s], acc[2 + i][j], 0, 0, 0);
        __builtin_amdgcn_s_setprio(0);

        // ---- boundary: per-wave counted drain, then global release --------
        if (kt < NT - 2)
            asm volatile("s_waitcnt vmcnt(4)" ::: "memory");  // keep B(kt+2,*) in flight
        else
            asm volatile("s_waitcnt vmcnt(0)" ::: "memory");  // tail drain
        __builtin_amdgcn_s_barrier();
    }

    // epilogue: 32x32 C/D layout col=lane&31, row=(reg&3)+8*(reg>>2)+4*(lane>>5)
    const int ccol = lane & 31;
    const int rsub = 4 * (lane >> 5);
    #pragma unroll
    for (int i = 0; i < 4; i++) {
        #pragma unroll
        for (int j = 0; j < 2; j++) {
            size_t base = (rA0 + wr + i * 32 + rsub) * (size_t)NN
                        + (rB0 + wc + j * 32 + ccol);
            #pragma unroll
            for (int r = 0; r < 16; r++) {
                const int row = (r & 3) + 8 * (r >> 2);
                C[base + (size_t)row * NN] = acc[i][j][r];
            }
        }
    }
}

// ---------------------------------------------------------------------------
extern "C" void kernel_launch(void* const* d_in, const int* in_sizes, int n_in,
                              void* d_out, int out_size, void* d_ws, size_t ws_size,
                              hipStream_t stream) {
    const float* x      = (const float*)d_in[0];   // [4,2048,4096]
    const float* weight = (const float*)d_in[1];   // [4096,4096]
    const float* hra_u  = (const float*)d_in[2];   // [4096,8]
    float* out = (float*)d_out;                    // [4,2048,4096]

    // workspace layout (all 16B aligned)
    char* w = (char*)d_ws;
    unsigned short* Xb = (unsigned short*)w;                              // 64 MB
    unsigned short* Wn = (unsigned short*)(w + (size_t)64 * 1024 * 1024); // 32 MB
    float* Y   = (float*)(w + (size_t)96 * 1024 * 1024);                  // 128 KB
    float* G   = Y + (size_t)D_IN * R_HH;
    float* inv = G + 64;

    static int attr_done = 0;
    if (!attr_done) {
        hipFuncSetAttribute((const void*)gemm256,
                            hipFuncAttributeMaxDynamicSharedMemorySize, 131072);
        attr_done = 1;
    }

    prep<<<1, 1024, 0, stream>>>(hra_u, G, inv);
    wu_gemv<<<D_OUT, 256, 0, stream>>>(weight, hra_u, inv, Y);
    wn_cast<<<D_OUT, 256, 0, stream>>>(weight, hra_u, inv, Y, G, Wn);

    const int n4 = M_ROWS * D_IN / 4;
    cast_x<<<4096, 256, 0, stream>>>((const float4*)x, (ushort4*)Xb, n4);

    gemm256<<<dim3((M_ROWS / 256) * (D_OUT / 256)), 512, 131072, stream>>>(Xb, Wn, out);
}